// Round 2
// baseline (588.619 us; speedup 1.0000x reference)
//
#include <hip/hip_runtime.h>
#include <hip/hip_bf16.h>

constexpr int N_   = 50000;
constexpr int E_   = 800000;
constexpr int G_   = 256;
constexpr int IN_  = 64;
constexpr int H_   = 8;
constexpr int OUT_ = 128;   // H*C
constexpr float NEG_SLOPE = 0.2f;

// ---- workspace layout (float offsets) ----
constexpr size_t OFF_X    = 0;                            // [N,128] transformed feats
constexpr size_t OFF_ASRC = OFF_X    + (size_t)N_*OUT_;   // [N,8]
constexpr size_t OFF_ADST = OFF_ASRC + (size_t)N_*H_;     // [N,8]
constexpr size_t OFF_S    = OFF_ADST + (size_t)N_*H_;     // [N,8]   (zeroed)
constexpr size_t OFF_ACC  = OFF_S    + (size_t)N_*H_;     // [N,128] (zeroed)
constexpr size_t OFF_GSUM = OFF_ACC  + (size_t)N_*OUT_;   // [G,128] (zeroed)
constexpr size_t OFF_GCNT = OFF_GSUM + (size_t)G_*OUT_;   // [G]     (zeroed)
constexpr size_t OFF_EMB  = OFF_GCNT + (size_t)G_;        // [N,128]
constexpr size_t OFF_GEMB = OFF_EMB  + (size_t)N_*OUT_;   // [G,128]
constexpr size_t ZERO_BEG = OFF_S;
constexpr size_t ZERO_END = OFF_EMB;

// K1: x = feat @ W_gat ; a_src/a_dst per-head dots. 16 nodes per 256-thread block.
__global__ void k_transform(const float* __restrict__ feat, const float* __restrict__ Wg,
                            const float* __restrict__ att_s, const float* __restrict__ att_d,
                            float* __restrict__ x, float* __restrict__ asrc,
                            float* __restrict__ adst) {
    const int base = blockIdx.x * 16;
    const int j    = threadIdx.x & 127;   // out channel
    const int half = threadIdx.x >> 7;    // 0/1 -> node sub-group

    __shared__ float f[16][IN_];
    for (int t = threadIdx.x; t < 16 * IN_; t += 256) {
        int ni = t >> 6, k = t & 63;
        f[ni][k] = feat[(size_t)(base + ni) * IN_ + k];
    }
    __syncthreads();

    float acc[8];
#pragma unroll
    for (int i = 0; i < 8; ++i) acc[i] = 0.f;
    for (int k = 0; k < IN_; ++k) {
        float w = Wg[k * OUT_ + j];
#pragma unroll
        for (int i = 0; i < 8; ++i) acc[i] += f[half * 8 + i][k] * w;
    }
    const float aw_s = att_s[j];
    const float aw_d = att_d[j];
#pragma unroll
    for (int i = 0; i < 8; ++i) {
        int n = base + half * 8 + i;
        x[(size_t)n * OUT_ + j] = acc[i];
        float ps = acc[i] * aw_s;
        float pd = acc[i] * aw_d;
#pragma unroll
        for (int m = 8; m >= 1; m >>= 1) {
            ps += __shfl_xor(ps, m, 16);
            pd += __shfl_xor(pd, m, 16);
        }
        if ((j & 15) == 0) {
            asrc[n * H_ + (j >> 4)] = ps;
            adst[n * H_ + (j >> 4)] = pd;
        }
    }
}

// K2: edge aggregation. 1 thread per (edge, channel); 2 edges per 256-thread block.
__global__ void k_edge(const int* __restrict__ src, const int* __restrict__ dst,
                       const float* __restrict__ x, const float* __restrict__ asrc,
                       const float* __restrict__ adst, float* __restrict__ acc,
                       float* __restrict__ s) {
    int t = blockIdx.x * 256 + threadIdx.x;     // < E*128 = 102.4M
    int e = t >> 7;
    int j = t & 127;
    int h = j >> 4;
    int sn = src[e];
    int dn = dst[e];
    float al = asrc[sn * H_ + h] + adst[dn * H_ + h];
    al = (al > 0.f) ? al : NEG_SLOPE * al;
    float w = __expf(al);
    float wx = w * x[(size_t)sn * OUT_ + j];
    unsafeAtomicAdd(&acc[(size_t)dn * OUT_ + j], wx);
    if ((j & 15) == 0) unsafeAtomicAdd(&s[dn * H_ + h], w);
}

// K3: self-loop fold-in, normalize, +bias, ELU -> emb (f32)
__global__ void k_norm(const float* __restrict__ x, const float* __restrict__ asrc,
                       const float* __restrict__ adst, const float* __restrict__ s,
                       const float* __restrict__ acc, const float* __restrict__ bias,
                       float* __restrict__ emb) {
    int t = blockIdx.x * 256 + threadIdx.x;     // < N*128
    int n = t >> 7;
    int j = t & 127;
    int h = j >> 4;
    float al = asrc[n * H_ + h] + adst[n * H_ + h];
    al = (al > 0.f) ? al : NEG_SLOPE * al;
    float w = __expf(al);
    float sv = s[n * H_ + h] + w;
    float o  = (acc[t] + w * x[t]) / sv + bias[j];
    emb[t] = (o > 0.f) ? o : expm1f(o);
}

// K4: per-graph node counts by binary search over sorted batch_index (1 block).
__global__ void k_counts(const int* __restrict__ batch, float* __restrict__ gcnt) {
    int g = threadIdx.x;
    int lo = 0, hi = N_;
    while (lo < hi) { int mid = (lo + hi) >> 1; if (batch[mid] < g) lo = mid + 1; else hi = mid; }
    int start = lo;
    lo = 0; hi = N_;
    while (lo < hi) { int mid = (lo + hi) >> 1; if (batch[mid] <= g) lo = mid + 1; else hi = mid; }
    gcnt[g] = (float)(lo - start);
}

// K5: mean-pool numerator. 32 nodes/block; run-length accumulate (batch sorted).
__global__ void k_pool(const float* __restrict__ emb, const int* __restrict__ batch,
                       float* __restrict__ gsum) {
    int j = threadIdx.x & 127;
    int half = threadIdx.x >> 7;
    int base = blockIdx.x * 32 + half * 16;
    float run = 0.f;
    int gcur = -1;
    for (int i = 0; i < 16; ++i) {
        int n = base + i;
        if (n >= N_) break;
        int g = batch[n];
        if (g != gcur) {
            if (gcur >= 0) unsafeAtomicAdd(&gsum[gcur * OUT_ + j], run);
            gcur = g; run = 0.f;
        }
        run += emb[(size_t)n * OUT_ + j];
    }
    if (gcur >= 0) unsafeAtomicAdd(&gsum[gcur * OUT_ + j], run);
}

// K6: graph_embedding = gsum / max(cnt,1); write f32 output + f32 ws copy.
__global__ void k_gemb(const float* __restrict__ gsum, const float* __restrict__ gcnt,
                       float* __restrict__ gemb, float* __restrict__ outg) {
    int t = blockIdx.x * 256 + threadIdx.x;     // < G*128
    int g = t >> 7;
    float v = gsum[t] / fmaxf(gcnt[g], 1.f);
    gemb[t] = v;
    outg[t] = v;
}

// K7: decoder MLP. 32 nodes per 256-thread block.
__global__ void k_dec(const float* __restrict__ emb, const float* __restrict__ gemb,
                      const int* __restrict__ batch, const float* __restrict__ W1,
                      const float* __restrict__ b1, const float* __restrict__ W2,
                      const float* __restrict__ b2, float* __restrict__ scores) {
    __shared__ float comb[32][256];   // 32 KB
    __shared__ float hbuf[32][129];   // padded vs bank conflicts
    int base = blockIdx.x * 32;

    for (int t = threadIdx.x; t < 32 * 256; t += 256) {
        int ni = t >> 8, k = t & 255;
        int n = base + ni;
        float v = 0.f;
        if (n < N_) v = (k < 128) ? emb[(size_t)n * OUT_ + k]
                                  : gemb[batch[n] * OUT_ + (k - 128)];
        comb[ni][k] = v;
    }
    __syncthreads();

    int j = threadIdx.x & 127;
    int half = threadIdx.x >> 7;
    float a[16];
#pragma unroll
    for (int i = 0; i < 16; ++i) a[i] = 0.f;
    for (int k = 0; k < 256; ++k) {
        float w = W1[k * 128 + j];
#pragma unroll
        for (int i = 0; i < 16; ++i) a[i] += comb[half * 16 + i][k] * w;
    }
    float bb = b1[j];
#pragma unroll
    for (int i = 0; i < 16; ++i) {
        float hv = a[i] + bb;
        hbuf[half * 16 + i][j] = (hv > 0.f) ? hv : 0.f;
    }
    __syncthreads();

    if (threadIdx.x < 32) {
        int n = base + threadIdx.x;
        if (n < N_) {
            float sum = b2[0];
            for (int k = 0; k < 128; ++k) sum += hbuf[threadIdx.x][k] * W2[k];
            scores[n] = sum;
        }
    }
}

extern "C" void kernel_launch(void* const* d_in, const int* in_sizes, int n_in,
                              void* d_out, int out_size, void* d_ws, size_t ws_size,
                              hipStream_t stream) {
    const float* feat   = (const float*)d_in[0];
    const int*   ei     = (const int*)d_in[1];
    const int*   batch  = (const int*)d_in[2];
    const float* Wg     = (const float*)d_in[3];
    const float* att_s  = (const float*)d_in[4];
    const float* att_d  = (const float*)d_in[5];
    const float* bias_g = (const float*)d_in[6];
    const float* W1     = (const float*)d_in[7];
    const float* b1     = (const float*)d_in[8];
    const float* W2     = (const float*)d_in[9];
    const float* b2     = (const float*)d_in[10];
    float* ws  = (float*)d_ws;
    float* out = (float*)d_out;

    const int* src = ei;        // edge_index[0]
    const int* dst = ei + E_;   // edge_index[1]

    hipMemsetAsync(ws + ZERO_BEG, 0, (ZERO_END - ZERO_BEG) * sizeof(float), stream);

    k_transform<<<N_ / 16, 256, 0, stream>>>(feat, Wg, att_s, att_d,
                                             ws + OFF_X, ws + OFF_ASRC, ws + OFF_ADST);
    k_edge<<<E_ / 2, 256, 0, stream>>>(src, dst, ws + OFF_X, ws + OFF_ASRC,
                                       ws + OFF_ADST, ws + OFF_ACC, ws + OFF_S);
    k_norm<<<(N_ * OUT_) / 256, 256, 0, stream>>>(ws + OFF_X, ws + OFF_ASRC,
                                                  ws + OFF_ADST, ws + OFF_S,
                                                  ws + OFF_ACC, bias_g, ws + OFF_EMB);
    k_counts<<<1, 256, 0, stream>>>(batch, ws + OFF_GCNT);
    k_pool<<<(N_ + 31) / 32, 256, 0, stream>>>(ws + OFF_EMB, batch, ws + OFF_GSUM);
    k_gemb<<<(G_ * OUT_) / 256, 256, 0, stream>>>(ws + OFF_GSUM, ws + OFF_GCNT,
                                                  ws + OFF_GEMB, out + N_);
    k_dec<<<(N_ + 31) / 32, 256, 0, stream>>>(ws + OFF_EMB, ws + OFF_GEMB, batch,
                                              W1, b1, W2, b2, out);
}

// Round 3
// 438.306 us; speedup vs baseline: 1.3429x; 1.3429x over previous
//
#include <hip/hip_runtime.h>
#include <hip/hip_bf16.h>

constexpr int N_   = 50000;
constexpr int E_   = 800000;
constexpr int G_   = 256;
constexpr int IN_  = 64;
constexpr int H_   = 8;
constexpr int OUT_ = 128;   // H*C
constexpr float NEG_SLOPE = 0.2f;

// ---- workspace layout (byte offsets, all 256B-aligned) ----
constexpr size_t OFF_X     = 0;                                  // [N,128] f32
constexpr size_t OFF_ASRC  = OFF_X     + (size_t)N_*OUT_*4;      // [N,8]  f32
constexpr size_t OFF_ADST  = OFF_ASRC  + (size_t)N_*H_*4;        // [N,8]  f32
constexpr size_t OFF_EMB   = OFF_ADST  + (size_t)N_*H_*4;        // [N,128] f32
constexpr size_t OFF_GSUM  = OFF_EMB   + (size_t)N_*OUT_*4;      // [G,128] f32 (zeroed)
constexpr size_t OFF_DEG   = OFF_GSUM  + (size_t)G_*OUT_*4;      // [N] int (zeroed)
constexpr size_t OFF_GEMB  = OFF_DEG   + (size_t)N_*4;           // [G,128] f32
constexpr size_t OFF_GCNT  = OFF_GEMB  + (size_t)G_*OUT_*4;      // [G] f32
constexpr size_t OFF_ROWS  = OFF_GCNT  + (size_t)G_*4 + 252;     // [N+1] int (pad to align)
constexpr size_t OFF_CUR   = OFF_ROWS  + (size_t)(N_+1)*4 + 252; // [N] int
constexpr size_t OFF_EIDX  = OFF_CUR   + (size_t)N_*4;           // [E] int (src per slot)
constexpr size_t ZERO_BEG  = OFF_GSUM;
constexpr size_t ZERO_LEN  = OFF_GEMB - OFF_GSUM;                // gsum + deg

// K1: x = feat @ W_gat ; a_src/a_dst per-head dots. 16 nodes per 256-thread block.
__global__ void k_transform(const float* __restrict__ feat, const float* __restrict__ Wg,
                            const float* __restrict__ att_s, const float* __restrict__ att_d,
                            float* __restrict__ x, float* __restrict__ asrc,
                            float* __restrict__ adst) {
    const int base = blockIdx.x * 16;
    const int j    = threadIdx.x & 127;
    const int half = threadIdx.x >> 7;

    __shared__ float f[16][IN_];
    for (int t = threadIdx.x; t < 16 * IN_; t += 256) {
        int ni = t >> 6, k = t & 63;
        f[ni][k] = feat[(size_t)(base + ni) * IN_ + k];
    }
    __syncthreads();

    float acc[8];
#pragma unroll
    for (int i = 0; i < 8; ++i) acc[i] = 0.f;
    for (int k = 0; k < IN_; ++k) {
        float w = Wg[k * OUT_ + j];
#pragma unroll
        for (int i = 0; i < 8; ++i) acc[i] += f[half * 8 + i][k] * w;
    }
    const float aw_s = att_s[j];
    const float aw_d = att_d[j];
#pragma unroll
    for (int i = 0; i < 8; ++i) {
        int n = base + half * 8 + i;
        x[(size_t)n * OUT_ + j] = acc[i];
        float ps = acc[i] * aw_s;
        float pd = acc[i] * aw_d;
#pragma unroll
        for (int m = 8; m >= 1; m >>= 1) {
            ps += __shfl_xor(ps, m, 16);
            pd += __shfl_xor(pd, m, 16);
        }
        if ((j & 15) == 0) {
            asrc[n * H_ + (j >> 4)] = ps;
            adst[n * H_ + (j >> 4)] = pd;
        }
    }
}

// K2a: in-degree histogram.
__global__ void k_hist(const int* __restrict__ dst, int* __restrict__ deg) {
    int e = blockIdx.x * 256 + threadIdx.x;
    if (e < E_) atomicAdd(&deg[dst[e]], 1);
}

// K2b: exclusive prefix sum of deg -> rowstart, cursor. One block, 256 threads.
__global__ void k_scan(const int* __restrict__ deg, int* __restrict__ rowstart,
                       int* __restrict__ cursor) {
    constexpr int CH = (N_ + 255) / 256;   // 196
    __shared__ int sums[256];
    const int t = threadIdx.x;
    const int beg = t * CH;
    const int end = min(beg + CH, N_);
    int s = 0;
    for (int i = beg; i < end; ++i) s += deg[i];
    sums[t] = s;
    __syncthreads();
    for (int off = 1; off < 256; off <<= 1) {
        int v = (t >= off) ? sums[t - off] : 0;
        __syncthreads();
        sums[t] += v;
        __syncthreads();
    }
    int run = (t == 0) ? 0 : sums[t - 1];
    for (int i = beg; i < end; ++i) {
        rowstart[i] = run;
        cursor[i]   = run;
        run += deg[i];
    }
    if (t == 255) rowstart[N_] = E_;
}

// K2c: scatter src indices into dst-grouped buckets.
__global__ void k_scatter(const int* __restrict__ src, const int* __restrict__ dst,
                          int* __restrict__ cursor, int* __restrict__ eidx) {
    int e = blockIdx.x * 256 + threadIdx.x;
    if (e < E_) {
        int pos = atomicAdd(&cursor[dst[e]], 1);
        eidx[pos] = src[e];
    }
}

// K3: CSR aggregation, one wave per dst node; fused self-loop+softmax-norm+bias+ELU.
__global__ void k_agg(const int* __restrict__ rowstart, const int* __restrict__ eidx,
                      const float* __restrict__ x, const float* __restrict__ asrc,
                      const float* __restrict__ adst, const float* __restrict__ bias,
                      float* __restrict__ emb) {
    const int dn   = blockIdx.x * 4 + (threadIdx.x >> 6);   // wave-uniform
    const int lane = threadIdx.x & 63;
    const int h    = lane >> 3;                              // head of channels 2*lane, 2*lane+1
    const float adst_h = adst[dn * H_ + h];

    const int beg = rowstart[dn];
    const int end = rowstart[dn + 1];

    float ax = 0.f, ay = 0.f, sw = 0.f;
    for (int i = beg; i < end; ++i) {
        int sn = eidx[i];
        float al = asrc[sn * H_ + h] + adst_h;
        al = (al > 0.f) ? al : NEG_SLOPE * al;
        float w = __expf(al);
        float2 xv = *(const float2*)&x[(size_t)sn * OUT_ + lane * 2];
        ax += w * xv.x;
        ay += w * xv.y;
        sw += w;
    }
    // self-loop
    {
        float al = asrc[dn * H_ + h] + adst_h;
        al = (al > 0.f) ? al : NEG_SLOPE * al;
        float w = __expf(al);
        float2 xv = *(const float2*)&x[(size_t)dn * OUT_ + lane * 2];
        ax += w * xv.x;
        ay += w * xv.y;
        sw += w;
    }
    float ox = ax / sw + bias[lane * 2];
    float oy = ay / sw + bias[lane * 2 + 1];
    ox = (ox > 0.f) ? ox : expm1f(ox);
    oy = (oy > 0.f) ? oy : expm1f(oy);
    *(float2*)&emb[(size_t)dn * OUT_ + lane * 2] = make_float2(ox, oy);
}

// K4: per-graph node counts by binary search over sorted batch_index (1 block).
__global__ void k_counts(const int* __restrict__ batch, float* __restrict__ gcnt) {
    int g = threadIdx.x;
    int lo = 0, hi = N_;
    while (lo < hi) { int mid = (lo + hi) >> 1; if (batch[mid] < g) lo = mid + 1; else hi = mid; }
    int start = lo;
    lo = 0; hi = N_;
    while (lo < hi) { int mid = (lo + hi) >> 1; if (batch[mid] <= g) lo = mid + 1; else hi = mid; }
    gcnt[g] = (float)(lo - start);
}

// K5: mean-pool numerator. 32 nodes/block; run-length accumulate (batch sorted).
__global__ void k_pool(const float* __restrict__ emb, const int* __restrict__ batch,
                       float* __restrict__ gsum) {
    int j = threadIdx.x & 127;
    int half = threadIdx.x >> 7;
    int base = blockIdx.x * 32 + half * 16;
    float run = 0.f;
    int gcur = -1;
    for (int i = 0; i < 16; ++i) {
        int n = base + i;
        if (n >= N_) break;
        int g = batch[n];
        if (g != gcur) {
            if (gcur >= 0) unsafeAtomicAdd(&gsum[gcur * OUT_ + j], run);
            gcur = g; run = 0.f;
        }
        run += emb[(size_t)n * OUT_ + j];
    }
    if (gcur >= 0) unsafeAtomicAdd(&gsum[gcur * OUT_ + j], run);
}

// K6: graph_embedding = gsum / max(cnt,1); write f32 output + ws copy.
__global__ void k_gemb(const float* __restrict__ gsum, const float* __restrict__ gcnt,
                       float* __restrict__ gemb, float* __restrict__ outg) {
    int t = blockIdx.x * 256 + threadIdx.x;
    int g = t >> 7;
    float v = gsum[t] / fmaxf(gcnt[g], 1.f);
    gemb[t] = v;
    outg[t] = v;
}

// K7: decoder MLP. 32 nodes per 256-thread block.
__global__ void k_dec(const float* __restrict__ emb, const float* __restrict__ gemb,
                      const int* __restrict__ batch, const float* __restrict__ W1,
                      const float* __restrict__ b1, const float* __restrict__ W2,
                      const float* __restrict__ b2, float* __restrict__ scores) {
    __shared__ float comb[32][256];
    __shared__ float hbuf[32][129];
    int base = blockIdx.x * 32;

    for (int t = threadIdx.x; t < 32 * 256; t += 256) {
        int ni = t >> 8, k = t & 255;
        int n = base + ni;
        float v = 0.f;
        if (n < N_) v = (k < 128) ? emb[(size_t)n * OUT_ + k]
                                  : gemb[batch[n] * OUT_ + (k - 128)];
        comb[ni][k] = v;
    }
    __syncthreads();

    int j = threadIdx.x & 127;
    int half = threadIdx.x >> 7;
    float a[16];
#pragma unroll
    for (int i = 0; i < 16; ++i) a[i] = 0.f;
    for (int k = 0; k < 256; ++k) {
        float w = W1[k * 128 + j];
#pragma unroll
        for (int i = 0; i < 16; ++i) a[i] += comb[half * 16 + i][k] * w;
    }
    float bb = b1[j];
#pragma unroll
    for (int i = 0; i < 16; ++i) {
        float hv = a[i] + bb;
        hbuf[half * 16 + i][j] = (hv > 0.f) ? hv : 0.f;
    }
    __syncthreads();

    if (threadIdx.x < 32) {
        int n = base + threadIdx.x;
        if (n < N_) {
            float sum = b2[0];
            for (int k = 0; k < 128; ++k) sum += hbuf[threadIdx.x][k] * W2[k];
            scores[n] = sum;
        }
    }
}

extern "C" void kernel_launch(void* const* d_in, const int* in_sizes, int n_in,
                              void* d_out, int out_size, void* d_ws, size_t ws_size,
                              hipStream_t stream) {
    const float* feat   = (const float*)d_in[0];
    const int*   ei     = (const int*)d_in[1];
    const int*   batch  = (const int*)d_in[2];
    const float* Wg     = (const float*)d_in[3];
    const float* att_s  = (const float*)d_in[4];
    const float* att_d  = (const float*)d_in[5];
    const float* bias_g = (const float*)d_in[6];
    const float* W1     = (const float*)d_in[7];
    const float* b1     = (const float*)d_in[8];
    const float* W2     = (const float*)d_in[9];
    const float* b2     = (const float*)d_in[10];
    char*  wsb = (char*)d_ws;
    float* out = (float*)d_out;

    const int* src = ei;        // edge_index[0]
    const int* dst = ei + E_;   // edge_index[1]

    float* X    = (float*)(wsb + OFF_X);
    float* ASRC = (float*)(wsb + OFF_ASRC);
    float* ADST = (float*)(wsb + OFF_ADST);
    float* EMB  = (float*)(wsb + OFF_EMB);
    float* GSUM = (float*)(wsb + OFF_GSUM);
    int*   DEG  = (int*)  (wsb + OFF_DEG);
    float* GEMB = (float*)(wsb + OFF_GEMB);
    float* GCNT = (float*)(wsb + OFF_GCNT);
    int*   ROWS = (int*)  (wsb + OFF_ROWS);
    int*   CUR  = (int*)  (wsb + OFF_CUR);
    int*   EIDX = (int*)  (wsb + OFF_EIDX);

    hipMemsetAsync(wsb + ZERO_BEG, 0, ZERO_LEN, stream);

    k_transform<<<N_ / 16, 256, 0, stream>>>(feat, Wg, att_s, att_d, X, ASRC, ADST);
    k_hist<<<(E_ + 255) / 256, 256, 0, stream>>>(dst, DEG);
    k_scan<<<1, 256, 0, stream>>>(DEG, ROWS, CUR);
    k_scatter<<<(E_ + 255) / 256, 256, 0, stream>>>(src, dst, CUR, EIDX);
    k_agg<<<N_ / 4, 256, 0, stream>>>(ROWS, EIDX, X, ASRC, ADST, bias_g, EMB);
    k_counts<<<1, 256, 0, stream>>>(batch, GCNT);
    k_pool<<<(N_ + 31) / 32, 256, 0, stream>>>(EMB, batch, GSUM);
    k_gemb<<<(G_ * OUT_) / 256, 256, 0, stream>>>(GSUM, GCNT, GEMB, out + N_);
    k_dec<<<(N_ + 31) / 32, 256, 0, stream>>>(EMB, GEMB, batch, W1, b1, W2, b2, out);
}

// Round 4
// 339.735 us; speedup vs baseline: 1.7326x; 1.2901x over previous
//
#include <hip/hip_runtime.h>
#include <hip/hip_bf16.h>

constexpr int N_   = 50000;
constexpr int E_   = 800000;
constexpr int G_   = 256;
constexpr int IN_  = 64;
constexpr int H_   = 8;
constexpr int OUT_ = 128;   // H*C
constexpr float NEG_SLOPE = 0.2f;
constexpr int NB_  = (N_ + 255) / 256;   // 196 scan blocks

// ---- workspace layout (byte offsets, all 256B-aligned) ----
constexpr size_t OFF_X     = 0;                                  // [N,128] f32
constexpr size_t OFF_ASRC  = OFF_X     + (size_t)N_*OUT_*4;      // [N,8]  f32
constexpr size_t OFF_ADST  = OFF_ASRC  + (size_t)N_*H_*4;        // [N,8]  f32
constexpr size_t OFF_EMB   = OFF_ADST  + (size_t)N_*H_*4;        // [N,128] f32
constexpr size_t OFF_GSUM  = OFF_EMB   + (size_t)N_*OUT_*4;      // [G,128] f32 (zeroed)
constexpr size_t OFF_DEG   = OFF_GSUM  + (size_t)G_*OUT_*4;      // [N] int (zeroed)
constexpr size_t OFF_GEMB  = OFF_DEG   + (size_t)N_*4;           // [G,128] f32
constexpr size_t OFF_GCNT  = OFF_GEMB  + (size_t)G_*OUT_*4;      // [G] f32
constexpr size_t OFF_ROWS  = OFF_GCNT  + (size_t)G_*4 + 252;     // [N+1] int
constexpr size_t OFF_CUR   = OFF_ROWS  + (size_t)(N_+1)*4 + 252; // [N] int
constexpr size_t OFF_EIDX  = OFF_CUR   + (size_t)N_*4;           // [E] int (src per slot)
constexpr size_t OFF_BSUM  = OFF_EIDX  + (size_t)E_*4;           // [NB] int
constexpr size_t OFF_BOFF  = OFF_BSUM  + (size_t)NB_*4 + 240;    // [NB] int
constexpr size_t ZERO_BEG  = OFF_GSUM;
constexpr size_t ZERO_LEN  = OFF_GEMB - OFF_GSUM;                // gsum + deg

// K1: x = feat @ W_gat ; a_src/a_dst per-head dots. 16 nodes per 256-thread block.
__global__ void k_transform(const float* __restrict__ feat, const float* __restrict__ Wg,
                            const float* __restrict__ att_s, const float* __restrict__ att_d,
                            float* __restrict__ x, float* __restrict__ asrc,
                            float* __restrict__ adst) {
    const int base = blockIdx.x * 16;
    const int j    = threadIdx.x & 127;
    const int half = threadIdx.x >> 7;

    __shared__ float f[16][IN_];
    for (int t = threadIdx.x; t < 16 * IN_; t += 256) {
        int ni = t >> 6, k = t & 63;
        f[ni][k] = feat[(size_t)(base + ni) * IN_ + k];
    }
    __syncthreads();

    float acc[8];
#pragma unroll
    for (int i = 0; i < 8; ++i) acc[i] = 0.f;
    for (int k = 0; k < IN_; ++k) {
        float w = Wg[k * OUT_ + j];
#pragma unroll
        for (int i = 0; i < 8; ++i) acc[i] += f[half * 8 + i][k] * w;
    }
    const float aw_s = att_s[j];
    const float aw_d = att_d[j];
#pragma unroll
    for (int i = 0; i < 8; ++i) {
        int n = base + half * 8 + i;
        x[(size_t)n * OUT_ + j] = acc[i];
        float ps = acc[i] * aw_s;
        float pd = acc[i] * aw_d;
#pragma unroll
        for (int m = 8; m >= 1; m >>= 1) {
            ps += __shfl_xor(ps, m, 16);
            pd += __shfl_xor(pd, m, 16);
        }
        if ((j & 15) == 0) {
            asrc[n * H_ + (j >> 4)] = ps;
            adst[n * H_ + (j >> 4)] = pd;
        }
    }
}

// K2a: in-degree histogram.
__global__ void k_hist(const int* __restrict__ dst, int* __restrict__ deg) {
    int e = blockIdx.x * 256 + threadIdx.x;
    if (e < E_) atomicAdd(&deg[dst[e]], 1);
}

// K2b-1: per-block sums of deg (256 elements per block).
__global__ void k_blocksum(const int* __restrict__ deg, int* __restrict__ bsum) {
    int i = blockIdx.x * 256 + threadIdx.x;
    int v = (i < N_) ? deg[i] : 0;
#pragma unroll
    for (int m = 32; m >= 1; m >>= 1) v += __shfl_xor(v, m, 64);
    __shared__ int ws[4];
    if ((threadIdx.x & 63) == 0) ws[threadIdx.x >> 6] = v;
    __syncthreads();
    if (threadIdx.x == 0) bsum[blockIdx.x] = ws[0] + ws[1] + ws[2] + ws[3];
}

// K2b-2: exclusive scan of the NB block sums (one block).
__global__ void k_scanb(const int* __restrict__ bsum, int* __restrict__ boff) {
    __shared__ int s[256];
    int t = threadIdx.x;
    int v = (t < NB_) ? bsum[t] : 0;
    s[t] = v;
    __syncthreads();
    for (int off = 1; off < 256; off <<= 1) {
        int u = (t >= off) ? s[t - off] : 0;
        __syncthreads();
        s[t] += u;
        __syncthreads();
    }
    if (t < NB_) boff[t] = s[t] - v;   // exclusive
}

// K2b-3: block-local exclusive scan + block offset -> rowstart, cursor.
__global__ void k_scanfin(const int* __restrict__ deg, const int* __restrict__ boff,
                          int* __restrict__ rowstart, int* __restrict__ cursor) {
    __shared__ int s[256];
    int t = threadIdx.x;
    int i = blockIdx.x * 256 + t;
    int v = (i < N_) ? deg[i] : 0;
    s[t] = v;
    __syncthreads();
    for (int off = 1; off < 256; off <<= 1) {
        int u = (t >= off) ? s[t - off] : 0;
        __syncthreads();
        s[t] += u;
        __syncthreads();
    }
    if (i < N_) {
        int r = boff[blockIdx.x] + s[t] - v;
        rowstart[i] = r;
        cursor[i]   = r;
    }
    if (i == N_ - 1) rowstart[N_] = E_;
}

// K2c: scatter src indices into dst-grouped buckets.
__global__ void k_scatter(const int* __restrict__ src, const int* __restrict__ dst,
                          int* __restrict__ cursor, int* __restrict__ eidx) {
    int e = blockIdx.x * 256 + threadIdx.x;
    if (e < E_) {
        int pos = atomicAdd(&cursor[dst[e]], 1);
        eidx[pos] = src[e];
    }
}

// K3: CSR aggregation, one wave per dst node; fused self-loop+softmax-norm+bias+ELU.
__global__ void k_agg(const int* __restrict__ rowstart, const int* __restrict__ eidx,
                      const float* __restrict__ x, const float* __restrict__ asrc,
                      const float* __restrict__ adst, const float* __restrict__ bias,
                      float* __restrict__ emb) {
    const int dn   = blockIdx.x * 4 + (threadIdx.x >> 6);   // wave-uniform
    const int lane = threadIdx.x & 63;
    const int h    = lane >> 3;                              // head of channels 2*lane, 2*lane+1
    const float adst_h = adst[dn * H_ + h];

    const int beg = rowstart[dn];
    const int end = rowstart[dn + 1];

    float ax = 0.f, ay = 0.f, sw = 0.f;
    for (int i = beg; i < end; ++i) {
        int sn = eidx[i];
        float al = asrc[sn * H_ + h] + adst_h;
        al = (al > 0.f) ? al : NEG_SLOPE * al;
        float w = __expf(al);
        float2 xv = *(const float2*)&x[(size_t)sn * OUT_ + lane * 2];
        ax += w * xv.x;
        ay += w * xv.y;
        sw += w;
    }
    // self-loop
    {
        float al = asrc[dn * H_ + h] + adst_h;
        al = (al > 0.f) ? al : NEG_SLOPE * al;
        float w = __expf(al);
        float2 xv = *(const float2*)&x[(size_t)dn * OUT_ + lane * 2];
        ax += w * xv.x;
        ay += w * xv.y;
        sw += w;
    }
    float ox = ax / sw + bias[lane * 2];
    float oy = ay / sw + bias[lane * 2 + 1];
    ox = (ox > 0.f) ? ox : expm1f(ox);
    oy = (oy > 0.f) ? oy : expm1f(oy);
    *(float2*)&emb[(size_t)dn * OUT_ + lane * 2] = make_float2(ox, oy);
}

// K4: per-graph node counts by binary search over sorted batch_index (1 block).
__global__ void k_counts(const int* __restrict__ batch, float* __restrict__ gcnt) {
    int g = threadIdx.x;
    int lo = 0, hi = N_;
    while (lo < hi) { int mid = (lo + hi) >> 1; if (batch[mid] < g) lo = mid + 1; else hi = mid; }
    int start = lo;
    lo = 0; hi = N_;
    while (lo < hi) { int mid = (lo + hi) >> 1; if (batch[mid] <= g) lo = mid + 1; else hi = mid; }
    gcnt[g] = (float)(lo - start);
}

// K5: mean-pool numerator. 32 nodes/block; run-length accumulate (batch sorted).
__global__ void k_pool(const float* __restrict__ emb, const int* __restrict__ batch,
                       float* __restrict__ gsum) {
    int j = threadIdx.x & 127;
    int half = threadIdx.x >> 7;
    int base = blockIdx.x * 32 + half * 16;
    float run = 0.f;
    int gcur = -1;
    for (int i = 0; i < 16; ++i) {
        int n = base + i;
        if (n >= N_) break;
        int g = batch[n];
        if (g != gcur) {
            if (gcur >= 0) unsafeAtomicAdd(&gsum[gcur * OUT_ + j], run);
            gcur = g; run = 0.f;
        }
        run += emb[(size_t)n * OUT_ + j];
    }
    if (gcur >= 0) unsafeAtomicAdd(&gsum[gcur * OUT_ + j], run);
}

// K6: graph_embedding = gsum / max(cnt,1); write f32 output + ws copy.
__global__ void k_gemb(const float* __restrict__ gsum, const float* __restrict__ gcnt,
                       float* __restrict__ gemb, float* __restrict__ outg) {
    int t = blockIdx.x * 256 + threadIdx.x;
    int g = t >> 7;
    float v = gsum[t] / fmaxf(gcnt[g], 1.f);
    gemb[t] = v;
    outg[t] = v;
}

// K7: decoder MLP. 32 nodes per 256-thread block.
__global__ void k_dec(const float* __restrict__ emb, const float* __restrict__ gemb,
                      const int* __restrict__ batch, const float* __restrict__ W1,
                      const float* __restrict__ b1, const float* __restrict__ W2,
                      const float* __restrict__ b2, float* __restrict__ scores) {
    __shared__ float comb[32][256];
    __shared__ float hbuf[32][129];
    int base = blockIdx.x * 32;

    for (int t = threadIdx.x; t < 32 * 256; t += 256) {
        int ni = t >> 8, k = t & 255;
        int n = base + ni;
        float v = 0.f;
        if (n < N_) v = (k < 128) ? emb[(size_t)n * OUT_ + k]
                                  : gemb[batch[n] * OUT_ + (k - 128)];
        comb[ni][k] = v;
    }
    __syncthreads();

    int j = threadIdx.x & 127;
    int half = threadIdx.x >> 7;
    float a[16];
#pragma unroll
    for (int i = 0; i < 16; ++i) a[i] = 0.f;
    for (int k = 0; k < 256; ++k) {
        float w = W1[k * 128 + j];
#pragma unroll
        for (int i = 0; i < 16; ++i) a[i] += comb[half * 16 + i][k] * w;
    }
    float bb = b1[j];
#pragma unroll
    for (int i = 0; i < 16; ++i) {
        float hv = a[i] + bb;
        hbuf[half * 16 + i][j] = (hv > 0.f) ? hv : 0.f;
    }
    __syncthreads();

    if (threadIdx.x < 32) {
        int n = base + threadIdx.x;
        if (n < N_) {
            float sum = b2[0];
            for (int k = 0; k < 128; ++k) sum += hbuf[threadIdx.x][k] * W2[k];
            scores[n] = sum;
        }
    }
}

extern "C" void kernel_launch(void* const* d_in, const int* in_sizes, int n_in,
                              void* d_out, int out_size, void* d_ws, size_t ws_size,
                              hipStream_t stream) {
    const float* feat   = (const float*)d_in[0];
    const int*   ei     = (const int*)d_in[1];
    const int*   batch  = (const int*)d_in[2];
    const float* Wg     = (const float*)d_in[3];
    const float* att_s  = (const float*)d_in[4];
    const float* att_d  = (const float*)d_in[5];
    const float* bias_g = (const float*)d_in[6];
    const float* W1     = (const float*)d_in[7];
    const float* b1     = (const float*)d_in[8];
    const float* W2     = (const float*)d_in[9];
    const float* b2     = (const float*)d_in[10];
    char*  wsb = (char*)d_ws;
    float* out = (float*)d_out;

    const int* src = ei;        // edge_index[0]
    const int* dst = ei + E_;   // edge_index[1]

    float* X    = (float*)(wsb + OFF_X);
    float* ASRC = (float*)(wsb + OFF_ASRC);
    float* ADST = (float*)(wsb + OFF_ADST);
    float* EMB  = (float*)(wsb + OFF_EMB);
    float* GSUM = (float*)(wsb + OFF_GSUM);
    int*   DEG  = (int*)  (wsb + OFF_DEG);
    float* GEMB = (float*)(wsb + OFF_GEMB);
    float* GCNT = (float*)(wsb + OFF_GCNT);
    int*   ROWS = (int*)  (wsb + OFF_ROWS);
    int*   CUR  = (int*)  (wsb + OFF_CUR);
    int*   EIDX = (int*)  (wsb + OFF_EIDX);
    int*   BSUM = (int*)  (wsb + OFF_BSUM);
    int*   BOFF = (int*)  (wsb + OFF_BOFF);

    hipMemsetAsync(wsb + ZERO_BEG, 0, ZERO_LEN, stream);

    k_transform<<<N_ / 16, 256, 0, stream>>>(feat, Wg, att_s, att_d, X, ASRC, ADST);
    k_hist<<<(E_ + 255) / 256, 256, 0, stream>>>(dst, DEG);
    k_blocksum<<<NB_, 256, 0, stream>>>(DEG, BSUM);
    k_scanb<<<1, 256, 0, stream>>>(BSUM, BOFF);
    k_scanfin<<<NB_, 256, 0, stream>>>(DEG, BOFF, ROWS, CUR);
    k_scatter<<<(E_ + 255) / 256, 256, 0, stream>>>(src, dst, CUR, EIDX);
    k_agg<<<N_ / 4, 256, 0, stream>>>(ROWS, EIDX, X, ASRC, ADST, bias_g, EMB);
    k_counts<<<1, 256, 0, stream>>>(batch, GCNT);
    k_pool<<<(N_ + 31) / 32, 256, 0, stream>>>(EMB, batch, GSUM);
    k_gemb<<<(G_ * OUT_) / 256, 256, 0, stream>>>(GSUM, GCNT, GEMB, out + N_);
    k_dec<<<(N_ + 31) / 32, 256, 0, stream>>>(EMB, GEMB, batch, W1, b1, W2, b2, out);
}

// Round 5
// 288.145 us; speedup vs baseline: 2.0428x; 1.1790x over previous
//
#include <hip/hip_runtime.h>
#include <hip/hip_bf16.h>

constexpr int N_   = 50000;
constexpr int E_   = 800000;
constexpr int G_   = 256;
constexpr int IN_  = 64;
constexpr int H_   = 8;
constexpr int OUT_ = 128;   // H*C
constexpr float NEG_SLOPE = 0.2f;
constexpr int NB_  = (N_ + 255) / 256;   // 196 scan blocks

// ---- workspace layout (byte offsets, all 256B-aligned) ----
constexpr size_t OFF_X     = 0;                                  // [N,128] f32
constexpr size_t OFF_ASRC  = OFF_X     + (size_t)N_*OUT_*4;      // [N,8]  f32
constexpr size_t OFF_ADST  = OFF_ASRC  + (size_t)N_*H_*4;        // [N,8]  f32
constexpr size_t OFF_EMB   = OFF_ADST  + (size_t)N_*H_*4;        // [N,128] f32
constexpr size_t OFF_GSUM  = OFF_EMB   + (size_t)N_*OUT_*4;      // [G,128] f32 (zeroed)
constexpr size_t OFF_DEG   = OFF_GSUM  + (size_t)G_*OUT_*4;      // [N] int (zeroed)
constexpr size_t OFF_GEMB  = OFF_DEG   + (size_t)N_*4;           // [G,128] f32
constexpr size_t OFF_GCNT  = OFF_GEMB  + (size_t)G_*OUT_*4;      // [G] f32
constexpr size_t OFF_ROWS  = OFF_GCNT  + (size_t)G_*4 + 252;     // [N+1] int
constexpr size_t OFF_CUR   = OFF_ROWS  + (size_t)(N_+1)*4 + 252; // [N] int
constexpr size_t OFF_EIDX  = OFF_CUR   + (size_t)N_*4;           // [E] int (src per slot)
constexpr size_t OFF_BSUM  = OFF_EIDX  + (size_t)E_*4;           // [NB] int
constexpr size_t OFF_BOFF  = OFF_BSUM  + (size_t)NB_*4 + 240;    // [NB] int
constexpr size_t OFF_GPART = OFF_BOFF  + (size_t)NB_*4 + 240;    // [G,128] f32
constexpr size_t ZERO_BEG  = OFF_GSUM;
constexpr size_t ZERO_LEN  = OFF_GEMB - OFF_GSUM;                // gsum + deg

// K1: x = feat @ W_gat ; a_src/a_dst per-head dots. 16 nodes per 256-thread block.
__global__ void k_transform(const float* __restrict__ feat, const float* __restrict__ Wg,
                            const float* __restrict__ att_s, const float* __restrict__ att_d,
                            float* __restrict__ x, float* __restrict__ asrc,
                            float* __restrict__ adst) {
    const int base = blockIdx.x * 16;
    const int j    = threadIdx.x & 127;
    const int half = threadIdx.x >> 7;

    __shared__ float f[16][IN_];
    for (int t = threadIdx.x; t < 16 * IN_; t += 256) {
        int ni = t >> 6, k = t & 63;
        f[ni][k] = feat[(size_t)(base + ni) * IN_ + k];
    }
    __syncthreads();

    float acc[8];
#pragma unroll
    for (int i = 0; i < 8; ++i) acc[i] = 0.f;
    for (int k = 0; k < IN_; ++k) {
        float w = Wg[k * OUT_ + j];
#pragma unroll
        for (int i = 0; i < 8; ++i) acc[i] += f[half * 8 + i][k] * w;
    }
    const float aw_s = att_s[j];
    const float aw_d = att_d[j];
#pragma unroll
    for (int i = 0; i < 8; ++i) {
        int n = base + half * 8 + i;
        x[(size_t)n * OUT_ + j] = acc[i];
        float ps = acc[i] * aw_s;
        float pd = acc[i] * aw_d;
#pragma unroll
        for (int m = 8; m >= 1; m >>= 1) {
            ps += __shfl_xor(ps, m, 16);
            pd += __shfl_xor(pd, m, 16);
        }
        if ((j & 15) == 0) {
            asrc[n * H_ + (j >> 4)] = ps;
            adst[n * H_ + (j >> 4)] = pd;
        }
    }
}

// K2a: in-degree histogram.
__global__ void k_hist(const int* __restrict__ dst, int* __restrict__ deg) {
    int e = blockIdx.x * 256 + threadIdx.x;
    if (e < E_) atomicAdd(&deg[dst[e]], 1);
}

// K2b-1: per-block sums of deg (256 elements per block).
__global__ void k_blocksum(const int* __restrict__ deg, int* __restrict__ bsum) {
    int i = blockIdx.x * 256 + threadIdx.x;
    int v = (i < N_) ? deg[i] : 0;
#pragma unroll
    for (int m = 32; m >= 1; m >>= 1) v += __shfl_xor(v, m, 64);
    __shared__ int ws[4];
    if ((threadIdx.x & 63) == 0) ws[threadIdx.x >> 6] = v;
    __syncthreads();
    if (threadIdx.x == 0) bsum[blockIdx.x] = ws[0] + ws[1] + ws[2] + ws[3];
}

// K2b-2: exclusive scan of the NB block sums (one block).
__global__ void k_scanb(const int* __restrict__ bsum, int* __restrict__ boff) {
    __shared__ int s[256];
    int t = threadIdx.x;
    int v = (t < NB_) ? bsum[t] : 0;
    s[t] = v;
    __syncthreads();
    for (int off = 1; off < 256; off <<= 1) {
        int u = (t >= off) ? s[t - off] : 0;
        __syncthreads();
        s[t] += u;
        __syncthreads();
    }
    if (t < NB_) boff[t] = s[t] - v;   // exclusive
}

// K2b-3: block-local exclusive scan + block offset -> rowstart, cursor.
__global__ void k_scanfin(const int* __restrict__ deg, const int* __restrict__ boff,
                          int* __restrict__ rowstart, int* __restrict__ cursor) {
    __shared__ int s[256];
    int t = threadIdx.x;
    int i = blockIdx.x * 256 + t;
    int v = (i < N_) ? deg[i] : 0;
    s[t] = v;
    __syncthreads();
    for (int off = 1; off < 256; off <<= 1) {
        int u = (t >= off) ? s[t - off] : 0;
        __syncthreads();
        s[t] += u;
        __syncthreads();
    }
    if (i < N_) {
        int r = boff[blockIdx.x] + s[t] - v;
        rowstart[i] = r;
        cursor[i]   = r;
    }
    if (i == N_ - 1) rowstart[N_] = E_;
}

// K2c: scatter src indices into dst-grouped buckets.
__global__ void k_scatter(const int* __restrict__ src, const int* __restrict__ dst,
                          int* __restrict__ cursor, int* __restrict__ eidx) {
    int e = blockIdx.x * 256 + threadIdx.x;
    if (e < E_) {
        int pos = atomicAdd(&cursor[dst[e]], 1);
        eidx[pos] = src[e];
    }
}

// K3: CSR aggregation, one wave per dst node; fused self-loop+softmax-norm+bias+ELU.
__global__ void k_agg(const int* __restrict__ rowstart, const int* __restrict__ eidx,
                      const float* __restrict__ x, const float* __restrict__ asrc,
                      const float* __restrict__ adst, const float* __restrict__ bias,
                      float* __restrict__ emb) {
    const int dn   = blockIdx.x * 4 + (threadIdx.x >> 6);   // wave-uniform
    const int lane = threadIdx.x & 63;
    const int h    = lane >> 3;                              // head of channels 2*lane, 2*lane+1
    const float adst_h = adst[dn * H_ + h];

    const int beg = rowstart[dn];
    const int end = rowstart[dn + 1];

    float ax = 0.f, ay = 0.f, sw = 0.f;
    for (int i = beg; i < end; ++i) {
        int sn = eidx[i];
        float al = asrc[sn * H_ + h] + adst_h;
        al = (al > 0.f) ? al : NEG_SLOPE * al;
        float w = __expf(al);
        float2 xv = *(const float2*)&x[(size_t)sn * OUT_ + lane * 2];
        ax += w * xv.x;
        ay += w * xv.y;
        sw += w;
    }
    // self-loop
    {
        float al = asrc[dn * H_ + h] + adst_h;
        al = (al > 0.f) ? al : NEG_SLOPE * al;
        float w = __expf(al);
        float2 xv = *(const float2*)&x[(size_t)dn * OUT_ + lane * 2];
        ax += w * xv.x;
        ay += w * xv.y;
        sw += w;
    }
    float ox = ax / sw + bias[lane * 2];
    float oy = ay / sw + bias[lane * 2 + 1];
    ox = (ox > 0.f) ? ox : expm1f(ox);
    oy = (oy > 0.f) ? oy : expm1f(oy);
    *(float2*)&emb[(size_t)dn * OUT_ + lane * 2] = make_float2(ox, oy);
}

// K4: per-graph node counts by binary search over sorted batch_index (1 block).
__global__ void k_counts(const int* __restrict__ batch, float* __restrict__ gcnt) {
    int g = threadIdx.x;
    int lo = 0, hi = N_;
    while (lo < hi) { int mid = (lo + hi) >> 1; if (batch[mid] < g) lo = mid + 1; else hi = mid; }
    int start = lo;
    lo = 0; hi = N_;
    while (lo < hi) { int mid = (lo + hi) >> 1; if (batch[mid] <= g) lo = mid + 1; else hi = mid; }
    gcnt[g] = (float)(lo - start);
}

// K5: mean-pool numerator. 32 nodes/block; run-length accumulate (batch sorted).
__global__ void k_pool(const float* __restrict__ emb, const int* __restrict__ batch,
                       float* __restrict__ gsum) {
    int j = threadIdx.x & 127;
    int half = threadIdx.x >> 7;
    int base = blockIdx.x * 32 + half * 16;
    float run = 0.f;
    int gcur = -1;
    for (int i = 0; i < 16; ++i) {
        int n = base + i;
        if (n >= N_) break;
        int g = batch[n];
        if (g != gcur) {
            if (gcur >= 0) unsafeAtomicAdd(&gsum[gcur * OUT_ + j], run);
            gcur = g; run = 0.f;
        }
        run += emb[(size_t)n * OUT_ + j];
    }
    if (gcur >= 0) unsafeAtomicAdd(&gsum[gcur * OUT_ + j], run);
}

// K6: graph_embedding = gsum / max(cnt,1); write f32 output + ws copy.
__global__ void k_gemb(const float* __restrict__ gsum, const float* __restrict__ gcnt,
                       float* __restrict__ gemb, float* __restrict__ outg) {
    int t = blockIdx.x * 256 + threadIdx.x;
    int g = t >> 7;
    float v = gsum[t] / fmaxf(gcnt[g], 1.f);
    gemb[t] = v;
    outg[t] = v;
}

// K6b: gpart[g][j] = b1[j] + sum_k gemb[g][k] * W1[(128+k)*128 + j]. 1 block/graph.
__global__ void k_gpart(const float* __restrict__ gemb, const float* __restrict__ W1,
                        const float* __restrict__ b1, float* __restrict__ gpart) {
    const int g = blockIdx.x;
    const int j = threadIdx.x;   // 128 threads
    __shared__ float ge[128];
    ge[j] = gemb[g * 128 + j];
    __syncthreads();
    float s = b1[j];
    const float* w = W1 + (size_t)128 * 128 + j;
    for (int k = 0; k < 128; ++k) s += ge[k] * w[(size_t)k * 128];
    gpart[g * 128 + j] = s;
}

// K7: decoder GEMM: h=relu(emb@W1a + gpart[batch]); scores=h@W2+b2.
// 64 nodes/block, 256 threads, thread tile = 8 nodes x 4 j.
__global__ __launch_bounds__(256) void k_dec2(const float* __restrict__ emb,
                                              const float* __restrict__ gpart,
                                              const int* __restrict__ batch,
                                              const float* __restrict__ W1,
                                              const float* __restrict__ W2,
                                              const float* __restrict__ b2,
                                              float* __restrict__ scores) {
    constexpr int STR = 68;               // row stride (floats), 272B: 16B aligned
    __shared__ float combT[128 * STR];    // 34.8 KB, k-major
    const int base = blockIdx.x * 64;

    for (int idx = threadIdx.x; idx < 64 * 128; idx += 256) {
        int nl = idx >> 7;        // node 0..63
        int k  = idx & 127;       // coalesced along k
        int n  = base + nl;
        combT[k * STR + nl] = (n < N_) ? emb[(size_t)n * 128 + k] : 0.f;
    }
    __syncthreads();

    const int tj = threadIdx.x & 31;   // j block: columns tj*4..tj*4+3
    const int tn = threadIdx.x >> 5;   // node group: nodes tn*8..tn*8+7

    float acc[8][4];
#pragma unroll
    for (int i = 0; i < 8; ++i)
#pragma unroll
        for (int jj = 0; jj < 4; ++jj) acc[i][jj] = 0.f;

    const float* w1p = W1 + tj * 4;
    const float* cb  = combT + tn * 8;
    for (int k = 0; k < 128; ++k) {
        float4 w  = *(const float4*)(w1p + (size_t)k * 128);
        float4 c0 = *(const float4*)(cb + k * STR);
        float4 c1 = *(const float4*)(cb + k * STR + 4);
        float cv[8] = {c0.x, c0.y, c0.z, c0.w, c1.x, c1.y, c1.z, c1.w};
        float wv[4] = {w.x, w.y, w.z, w.w};
#pragma unroll
        for (int i = 0; i < 8; ++i)
#pragma unroll
            for (int jj = 0; jj < 4; ++jj)
                acc[i][jj] = fmaf(cv[i], wv[jj], acc[i][jj]);
    }

    float4 w2v = *(const float4*)(W2 + tj * 4);
    const float w2a[4] = {w2v.x, w2v.y, w2v.z, w2v.w};
    const float b2v = b2[0];

#pragma unroll
    for (int i = 0; i < 8; ++i) {
        int n = base + tn * 8 + i;
        if (n >= N_) continue;
        int g = batch[n];
        float4 gp = *(const float4*)(gpart + (size_t)g * 128 + tj * 4);
        const float gpa[4] = {gp.x, gp.y, gp.z, gp.w};
        float v = 0.f;
#pragma unroll
        for (int jj = 0; jj < 4; ++jj) {
            float h = acc[i][jj] + gpa[jj];
            h = (h > 0.f) ? h : 0.f;
            v = fmaf(h, w2a[jj], v);
        }
#pragma unroll
        for (int m = 16; m >= 1; m >>= 1) v += __shfl_xor(v, m, 64);
        if (tj == 0) scores[n] = v + b2v;
    }
}

extern "C" void kernel_launch(void* const* d_in, const int* in_sizes, int n_in,
                              void* d_out, int out_size, void* d_ws, size_t ws_size,
                              hipStream_t stream) {
    const float* feat   = (const float*)d_in[0];
    const int*   ei     = (const int*)d_in[1];
    const int*   batch  = (const int*)d_in[2];
    const float* Wg     = (const float*)d_in[3];
    const float* att_s  = (const float*)d_in[4];
    const float* att_d  = (const float*)d_in[5];
    const float* bias_g = (const float*)d_in[6];
    const float* W1     = (const float*)d_in[7];
    const float* b1     = (const float*)d_in[8];
    const float* W2     = (const float*)d_in[9];
    const float* b2     = (const float*)d_in[10];
    char*  wsb = (char*)d_ws;
    float* out = (float*)d_out;

    const int* src = ei;        // edge_index[0]
    const int* dst = ei + E_;   // edge_index[1]

    float* X     = (float*)(wsb + OFF_X);
    float* ASRC  = (float*)(wsb + OFF_ASRC);
    float* ADST  = (float*)(wsb + OFF_ADST);
    float* EMB   = (float*)(wsb + OFF_EMB);
    float* GSUM  = (float*)(wsb + OFF_GSUM);
    int*   DEG   = (int*)  (wsb + OFF_DEG);
    float* GEMB  = (float*)(wsb + OFF_GEMB);
    float* GCNT  = (float*)(wsb + OFF_GCNT);
    int*   ROWS  = (int*)  (wsb + OFF_ROWS);
    int*   CUR   = (int*)  (wsb + OFF_CUR);
    int*   EIDX  = (int*)  (wsb + OFF_EIDX);
    int*   BSUM  = (int*)  (wsb + OFF_BSUM);
    int*   BOFF  = (int*)  (wsb + OFF_BOFF);
    float* GPART = (float*)(wsb + OFF_GPART);

    hipMemsetAsync(wsb + ZERO_BEG, 0, ZERO_LEN, stream);

    k_transform<<<N_ / 16, 256, 0, stream>>>(feat, Wg, att_s, att_d, X, ASRC, ADST);
    k_hist<<<(E_ + 255) / 256, 256, 0, stream>>>(dst, DEG);
    k_blocksum<<<NB_, 256, 0, stream>>>(DEG, BSUM);
    k_scanb<<<1, 256, 0, stream>>>(BSUM, BOFF);
    k_scanfin<<<NB_, 256, 0, stream>>>(DEG, BOFF, ROWS, CUR);
    k_scatter<<<(E_ + 255) / 256, 256, 0, stream>>>(src, dst, CUR, EIDX);
    k_agg<<<N_ / 4, 256, 0, stream>>>(ROWS, EIDX, X, ASRC, ADST, bias_g, EMB);
    k_counts<<<1, 256, 0, stream>>>(batch, GCNT);
    k_pool<<<(N_ + 31) / 32, 256, 0, stream>>>(EMB, batch, GSUM);
    k_gemb<<<(G_ * OUT_) / 256, 256, 0, stream>>>(GSUM, GCNT, GEMB, out + N_);
    k_gpart<<<G_, 128, 0, stream>>>(GEMB, W1, b1, GPART);
    k_dec2<<<(N_ + 63) / 64, 256, 0, stream>>>(EMB, GPART, batch, W1, W2, b2, out);
}

// Round 6
// 245.930 us; speedup vs baseline: 2.3934x; 1.1717x over previous
//
#include <hip/hip_runtime.h>
#include <hip/hip_bf16.h>
#include <hip/hip_fp16.h>

constexpr int N_   = 50000;
constexpr int E_   = 800000;
constexpr int G_   = 256;
constexpr int IN_  = 64;
constexpr int H_   = 8;
constexpr int OUT_ = 128;   // H*C
constexpr float NEG_SLOPE = 0.2f;
constexpr int NB_  = (N_ + 255) / 256;   // 196 scan blocks

// ---- workspace layout (byte offsets, all 256B-aligned) ----
constexpr size_t OFF_X     = 0;                                  // [N,128] f16 (gather table)
constexpr size_t OFF_ASRC  = OFF_X     + (size_t)N_*OUT_*4;      // [N,8]  f32
constexpr size_t OFF_ADST  = OFF_ASRC  + (size_t)N_*H_*4;        // [N,8]  f32
constexpr size_t OFF_EMB   = OFF_ADST  + (size_t)N_*H_*4;        // [N,128] f32
constexpr size_t OFF_GSUM  = OFF_EMB   + (size_t)N_*OUT_*4;      // [G,128] f32 (zeroed)
constexpr size_t OFF_DEG   = OFF_GSUM  + (size_t)G_*OUT_*4;      // [N] int (zeroed)
constexpr size_t OFF_GEMB  = OFF_DEG   + (size_t)N_*4;           // [G,128] f32
constexpr size_t OFF_GCNT  = OFF_GEMB  + (size_t)G_*OUT_*4;      // [G] f32
constexpr size_t OFF_ROWS  = OFF_GCNT  + (size_t)G_*4 + 252;     // [N+1] int
constexpr size_t OFF_CUR   = OFF_ROWS  + (size_t)(N_+1)*4 + 252; // [N] int
constexpr size_t OFF_EIDX  = OFF_CUR   + (size_t)N_*4;           // [E] int (src per slot)
constexpr size_t OFF_BSUM  = OFF_EIDX  + (size_t)E_*4;           // [NB] int
constexpr size_t OFF_BOFF  = OFF_BSUM  + (size_t)NB_*4 + 240;    // [NB] int
constexpr size_t OFF_GPART = OFF_BOFF  + (size_t)NB_*4 + 240;    // [G,128] f32
constexpr size_t ZERO_BEG  = OFF_GSUM;
constexpr size_t ZERO_LEN  = OFF_GEMB - OFF_GSUM;                // gsum + deg

// K1: x = feat @ W_gat (f16 out); a_src/a_dst per-head dots. 16 nodes/block.
__global__ void k_transform(const float* __restrict__ feat, const float* __restrict__ Wg,
                            const float* __restrict__ att_s, const float* __restrict__ att_d,
                            __half* __restrict__ xh, float* __restrict__ asrc,
                            float* __restrict__ adst) {
    const int base = blockIdx.x * 16;
    const int j    = threadIdx.x & 127;
    const int half = threadIdx.x >> 7;

    __shared__ float f[16][IN_];
    for (int t = threadIdx.x; t < 16 * IN_; t += 256) {
        int ni = t >> 6, k = t & 63;
        f[ni][k] = feat[(size_t)(base + ni) * IN_ + k];
    }
    __syncthreads();

    float acc[8];
#pragma unroll
    for (int i = 0; i < 8; ++i) acc[i] = 0.f;
    for (int k = 0; k < IN_; ++k) {
        float w = Wg[k * OUT_ + j];
#pragma unroll
        for (int i = 0; i < 8; ++i) acc[i] += f[half * 8 + i][k] * w;
    }
    const float aw_s = att_s[j];
    const float aw_d = att_d[j];
#pragma unroll
    for (int i = 0; i < 8; ++i) {
        int n = base + half * 8 + i;
        xh[(size_t)n * OUT_ + j] = __float2half(acc[i]);
        float ps = acc[i] * aw_s;
        float pd = acc[i] * aw_d;
#pragma unroll
        for (int m = 8; m >= 1; m >>= 1) {
            ps += __shfl_xor(ps, m, 16);
            pd += __shfl_xor(pd, m, 16);
        }
        if ((j & 15) == 0) {
            asrc[n * H_ + (j >> 4)] = ps;
            adst[n * H_ + (j >> 4)] = pd;
        }
    }
}

// K2a: in-degree histogram.
__global__ void k_hist(const int* __restrict__ dst, int* __restrict__ deg) {
    int e = blockIdx.x * 256 + threadIdx.x;
    if (e < E_) atomicAdd(&deg[dst[e]], 1);
}

// K2b-1: per-block sums of deg (256 elements per block).
__global__ void k_blocksum(const int* __restrict__ deg, int* __restrict__ bsum) {
    int i = blockIdx.x * 256 + threadIdx.x;
    int v = (i < N_) ? deg[i] : 0;
#pragma unroll
    for (int m = 32; m >= 1; m >>= 1) v += __shfl_xor(v, m, 64);
    __shared__ int ws[4];
    if ((threadIdx.x & 63) == 0) ws[threadIdx.x >> 6] = v;
    __syncthreads();
    if (threadIdx.x == 0) bsum[blockIdx.x] = ws[0] + ws[1] + ws[2] + ws[3];
}

// K2b-2: exclusive scan of the NB block sums (one block).
__global__ void k_scanb(const int* __restrict__ bsum, int* __restrict__ boff) {
    __shared__ int s[256];
    int t = threadIdx.x;
    int v = (t < NB_) ? bsum[t] : 0;
    s[t] = v;
    __syncthreads();
    for (int off = 1; off < 256; off <<= 1) {
        int u = (t >= off) ? s[t - off] : 0;
        __syncthreads();
        s[t] += u;
        __syncthreads();
    }
    if (t < NB_) boff[t] = s[t] - v;   // exclusive
}

// K2b-3: block-local exclusive scan + block offset -> rowstart, cursor.
__global__ void k_scanfin(const int* __restrict__ deg, const int* __restrict__ boff,
                          int* __restrict__ rowstart, int* __restrict__ cursor) {
    __shared__ int s[256];
    int t = threadIdx.x;
    int i = blockIdx.x * 256 + t;
    int v = (i < N_) ? deg[i] : 0;
    s[t] = v;
    __syncthreads();
    for (int off = 1; off < 256; off <<= 1) {
        int u = (t >= off) ? s[t - off] : 0;
        __syncthreads();
        s[t] += u;
        __syncthreads();
    }
    if (i < N_) {
        int r = boff[blockIdx.x] + s[t] - v;
        rowstart[i] = r;
        cursor[i]   = r;
    }
    if (i == N_ - 1) rowstart[N_] = E_;
}

// K2c: scatter src indices into dst-grouped buckets.
__global__ void k_scatter(const int* __restrict__ src, const int* __restrict__ dst,
                          int* __restrict__ cursor, int* __restrict__ eidx) {
    int e = blockIdx.x * 256 + threadIdx.x;
    if (e < E_) {
        int pos = atomicAdd(&cursor[dst[e]], 1);
        eidx[pos] = src[e];
    }
}

// K3: CSR aggregation (f16 gather), one wave per dst; fused softmax-norm+bias+ELU.
__global__ void k_agg(const int* __restrict__ rowstart, const int* __restrict__ eidx,
                      const __half* __restrict__ xh, const float* __restrict__ asrc,
                      const float* __restrict__ adst, const float* __restrict__ bias,
                      float* __restrict__ emb) {
    const int dn   = blockIdx.x * 4 + (threadIdx.x >> 6);   // wave-uniform
    const int lane = threadIdx.x & 63;
    const int h    = lane >> 3;
    const float adst_h = adst[dn * H_ + h];

    const int beg = rowstart[dn];
    const int end = rowstart[dn + 1];

    float ax = 0.f, ay = 0.f, sw = 0.f;
    int i = beg;
    for (; i + 1 < end; i += 2) {
        int s0 = eidx[i];
        int s1 = eidx[i + 1];
        float a0 = asrc[s0 * H_ + h] + adst_h;
        float a1 = asrc[s1 * H_ + h] + adst_h;
        a0 = (a0 > 0.f) ? a0 : NEG_SLOPE * a0;
        a1 = (a1 > 0.f) ? a1 : NEG_SLOPE * a1;
        float w0 = __expf(a0);
        float w1 = __expf(a1);
        __half2 x0 = *(const __half2*)&xh[(size_t)s0 * OUT_ + lane * 2];
        __half2 x1 = *(const __half2*)&xh[(size_t)s1 * OUT_ + lane * 2];
        float2 f0 = __half22float2(x0);
        float2 f1 = __half22float2(x1);
        ax = fmaf(w0, f0.x, fmaf(w1, f1.x, ax));
        ay = fmaf(w0, f0.y, fmaf(w1, f1.y, ay));
        sw += w0 + w1;
    }
    if (i < end) {
        int s0 = eidx[i];
        float a0 = asrc[s0 * H_ + h] + adst_h;
        a0 = (a0 > 0.f) ? a0 : NEG_SLOPE * a0;
        float w0 = __expf(a0);
        __half2 x0 = *(const __half2*)&xh[(size_t)s0 * OUT_ + lane * 2];
        float2 f0 = __half22float2(x0);
        ax = fmaf(w0, f0.x, ax);
        ay = fmaf(w0, f0.y, ay);
        sw += w0;
    }
    // self-loop
    {
        float al = asrc[dn * H_ + h] + adst_h;
        al = (al > 0.f) ? al : NEG_SLOPE * al;
        float w = __expf(al);
        __half2 xv = *(const __half2*)&xh[(size_t)dn * OUT_ + lane * 2];
        float2 fv = __half22float2(xv);
        ax = fmaf(w, fv.x, ax);
        ay = fmaf(w, fv.y, ay);
        sw += w;
    }
    float ox = ax / sw + bias[lane * 2];
    float oy = ay / sw + bias[lane * 2 + 1];
    ox = (ox > 0.f) ? ox : expm1f(ox);
    oy = (oy > 0.f) ? oy : expm1f(oy);
    *(float2*)&emb[(size_t)dn * OUT_ + lane * 2] = make_float2(ox, oy);
}

// K4: per-graph node counts by binary search over sorted batch_index (1 block).
__global__ void k_counts(const int* __restrict__ batch, float* __restrict__ gcnt) {
    int g = threadIdx.x;
    int lo = 0, hi = N_;
    while (lo < hi) { int mid = (lo + hi) >> 1; if (batch[mid] < g) lo = mid + 1; else hi = mid; }
    int start = lo;
    lo = 0; hi = N_;
    while (lo < hi) { int mid = (lo + hi) >> 1; if (batch[mid] <= g) lo = mid + 1; else hi = mid; }
    gcnt[g] = (float)(lo - start);
}

// K5: mean-pool numerator. 32 nodes/block; run-length accumulate (batch sorted).
__global__ void k_pool(const float* __restrict__ emb, const int* __restrict__ batch,
                       float* __restrict__ gsum) {
    int j = threadIdx.x & 127;
    int half = threadIdx.x >> 7;
    int base = blockIdx.x * 32 + half * 16;
    float run = 0.f;
    int gcur = -1;
    for (int i = 0; i < 16; ++i) {
        int n = base + i;
        if (n >= N_) break;
        int g = batch[n];
        if (g != gcur) {
            if (gcur >= 0) unsafeAtomicAdd(&gsum[gcur * OUT_ + j], run);
            gcur = g; run = 0.f;
        }
        run += emb[(size_t)n * OUT_ + j];
    }
    if (gcur >= 0) unsafeAtomicAdd(&gsum[gcur * OUT_ + j], run);
}

// K6: graph_embedding = gsum / max(cnt,1); write f32 output + ws copy.
__global__ void k_gemb(const float* __restrict__ gsum, const float* __restrict__ gcnt,
                       float* __restrict__ gemb, float* __restrict__ outg) {
    int t = blockIdx.x * 256 + threadIdx.x;
    int g = t >> 7;
    float v = gsum[t] / fmaxf(gcnt[g], 1.f);
    gemb[t] = v;
    outg[t] = v;
}

// K6b: gpart[g][j] = b1[j] + sum_k gemb[g][k] * W1[(128+k)*128 + j]. 1 block/graph.
__global__ void k_gpart(const float* __restrict__ gemb, const float* __restrict__ W1,
                        const float* __restrict__ b1, float* __restrict__ gpart) {
    const int g = blockIdx.x;
    const int j = threadIdx.x;   // 128 threads
    __shared__ float ge[128];
    ge[j] = gemb[g * 128 + j];
    __syncthreads();
    float s = b1[j];
    const float* w = W1 + (size_t)128 * 128 + j;
    for (int k = 0; k < 128; ++k) s += ge[k] * w[(size_t)k * 128];
    gpart[g * 128 + j] = s;
}

// K7: decoder GEMM: h=relu(emb@W1a + gpart[batch]); scores=h@W2+b2.
// 64 nodes/block, 256 threads, thread tile = 8 nodes x 4 j.
__global__ __launch_bounds__(256) void k_dec2(const float* __restrict__ emb,
                                              const float* __restrict__ gpart,
                                              const int* __restrict__ batch,
                                              const float* __restrict__ W1,
                                              const float* __restrict__ W2,
                                              const float* __restrict__ b2,
                                              float* __restrict__ scores) {
    constexpr int STR = 68;               // row stride (floats), 272B: 16B aligned
    __shared__ float combT[128 * STR];    // 34.8 KB, k-major
    const int base = blockIdx.x * 64;

    for (int idx = threadIdx.x; idx < 64 * 128; idx += 256) {
        int nl = idx >> 7;        // node 0..63
        int k  = idx & 127;       // coalesced along k
        int n  = base + nl;
        combT[k * STR + nl] = (n < N_) ? emb[(size_t)n * 128 + k] : 0.f;
    }
    __syncthreads();

    const int tj = threadIdx.x & 31;   // j block: columns tj*4..tj*4+3
    const int tn = threadIdx.x >> 5;   // node group: nodes tn*8..tn*8+7

    float acc[8][4];
#pragma unroll
    for (int i = 0; i < 8; ++i)
#pragma unroll
        for (int jj = 0; jj < 4; ++jj) acc[i][jj] = 0.f;

    const float* w1p = W1 + tj * 4;
    const float* cb  = combT + tn * 8;
    for (int k = 0; k < 128; ++k) {
        float4 w  = *(const float4*)(w1p + (size_t)k * 128);
        float4 c0 = *(const float4*)(cb + k * STR);
        float4 c1 = *(const float4*)(cb + k * STR + 4);
        float cv[8] = {c0.x, c0.y, c0.z, c0.w, c1.x, c1.y, c1.z, c1.w};
        float wv[4] = {w.x, w.y, w.z, w.w};
#pragma unroll
        for (int i = 0; i < 8; ++i)
#pragma unroll
            for (int jj = 0; jj < 4; ++jj)
                acc[i][jj] = fmaf(cv[i], wv[jj], acc[i][jj]);
    }

    float4 w2v = *(const float4*)(W2 + tj * 4);
    const float w2a[4] = {w2v.x, w2v.y, w2v.z, w2v.w};
    const float b2v = b2[0];

#pragma unroll
    for (int i = 0; i < 8; ++i) {
        int n = base + tn * 8 + i;
        if (n >= N_) continue;
        int g = batch[n];
        float4 gp = *(const float4*)(gpart + (size_t)g * 128 + tj * 4);
        const float gpa[4] = {gp.x, gp.y, gp.z, gp.w};
        float v = 0.f;
#pragma unroll
        for (int jj = 0; jj < 4; ++jj) {
            float h = acc[i][jj] + gpa[jj];
            h = (h > 0.f) ? h : 0.f;
            v = fmaf(h, w2a[jj], v);
        }
#pragma unroll
        for (int m = 16; m >= 1; m >>= 1) v += __shfl_xor(v, m, 64);
        if (tj == 0) scores[n] = v + b2v;
    }
}

extern "C" void kernel_launch(void* const* d_in, const int* in_sizes, int n_in,
                              void* d_out, int out_size, void* d_ws, size_t ws_size,
                              hipStream_t stream) {
    const float* feat   = (const float*)d_in[0];
    const int*   ei     = (const int*)d_in[1];
    const int*   batch  = (const int*)d_in[2];
    const float* Wg     = (const float*)d_in[3];
    const float* att_s  = (const float*)d_in[4];
    const float* att_d  = (const float*)d_in[5];
    const float* bias_g = (const float*)d_in[6];
    const float* W1     = (const float*)d_in[7];
    const float* b1     = (const float*)d_in[8];
    const float* W2     = (const float*)d_in[9];
    const float* b2     = (const float*)d_in[10];
    char*  wsb = (char*)d_ws;
    float* out = (float*)d_out;

    const int* src = ei;        // edge_index[0]
    const int* dst = ei + E_;   // edge_index[1]

    __half* XH   = (__half*)(wsb + OFF_X);
    float* ASRC  = (float*)(wsb + OFF_ASRC);
    float* ADST  = (float*)(wsb + OFF_ADST);
    float* EMB   = (float*)(wsb + OFF_EMB);
    float* GSUM  = (float*)(wsb + OFF_GSUM);
    int*   DEG   = (int*)  (wsb + OFF_DEG);
    float* GEMB  = (float*)(wsb + OFF_GEMB);
    float* GCNT  = (float*)(wsb + OFF_GCNT);
    int*   ROWS  = (int*)  (wsb + OFF_ROWS);
    int*   CUR   = (int*)  (wsb + OFF_CUR);
    int*   EIDX  = (int*)  (wsb + OFF_EIDX);
    int*   BSUM  = (int*)  (wsb + OFF_BSUM);
    int*   BOFF  = (int*)  (wsb + OFF_BOFF);
    float* GPART = (float*)(wsb + OFF_GPART);

    hipMemsetAsync(wsb + ZERO_BEG, 0, ZERO_LEN, stream);

    k_transform<<<N_ / 16, 256, 0, stream>>>(feat, Wg, att_s, att_d, XH, ASRC, ADST);
    k_hist<<<(E_ + 255) / 256, 256, 0, stream>>>(dst, DEG);
    k_blocksum<<<NB_, 256, 0, stream>>>(DEG, BSUM);
    k_scanb<<<1, 256, 0, stream>>>(BSUM, BOFF);
    k_scanfin<<<NB_, 256, 0, stream>>>(DEG, BOFF, ROWS, CUR);
    k_scatter<<<(E_ + 255) / 256, 256, 0, stream>>>(src, dst, CUR, EIDX);
    k_agg<<<N_ / 4, 256, 0, stream>>>(ROWS, EIDX, XH, ASRC, ADST, bias_g, EMB);
    k_counts<<<1, 256, 0, stream>>>(batch, GCNT);
    k_pool<<<(N_ + 31) / 32, 256, 0, stream>>>(EMB, batch, GSUM);
    k_gemb<<<(G_ * OUT_) / 256, 256, 0, stream>>>(GSUM, GCNT, GEMB, out + N_);
    k_gpart<<<G_, 128, 0, stream>>>(GEMB, W1, b1, GPART);
    k_dec2<<<(N_ + 63) / 64, 256, 0, stream>>>(EMB, GPART, batch, W1, W2, b2, out);
}